// Round 7
// baseline (342.880 us; speedup 1.0000x reference)
//
#include <hip/hip_runtime.h>
#include <hip/hip_bf16.h>
#include <stdint.h>

// B=8 L=8192 C=384 DIN=128 HID=512, tokens=65536, bands(16 tok)=4096.
// softmax over size-1 axis == 1 -> attention out == v -> fold Wc = Wv@Wp.
// z = y + gelu(LN2(y)@W1+bm1)@W2 + bm2,  y = LN1(x)@Wc + bc.
// R12 == R11 resubmit (round 6 bench was an infra failure, not a kernel
// verdict; source re-audited for OOB/hang: none).
// R11: structural reset. The 1024-thr/159KB-LDS shape forced 1 block/CU,
// 3 vmcnt(0)-drain barriers, 16-wave lockstep, and a 64-arch-VGPR ceiling
// the 8-wide MFMA unrolls overflow -> 194us at 5% MFMA / 9% HBM (latency).
// Weights total ~360KB = L2-resident chip-wide -> read B-fragments DIRECTLY
// from global (Common-mistake #7: don't LDS-stage what L2 serves). Blocks
// are now 256 thr / 4 waves / 4.6KB LDS, grid 1024, ZERO __syncthreads:
// waves fully independent, blocks overlap, no staging drains. WcT colsum
// moves to a tiny csscalc kernel; biases are per-lane global loads. prep
// writes unpadded 16B-aligned strides (384/128/64) - no banks to dodge.

typedef __attribute__((ext_vector_type(8))) short bf16x8;
typedef __attribute__((ext_vector_type(4))) float f32x4;

__device__ __forceinline__ short f2bf(float f) {
  union { float f; unsigned u; } a; a.f = f;
  unsigned u = a.u;
  u += 0x7fffu + ((u >> 16) & 1u);   // RNE, finite inputs
  return (short)(u >> 16);
}
__device__ __forceinline__ float bf2f(short s) {
  union { unsigned u; float f; } a; a.u = ((unsigned)(unsigned short)s) << 16;
  return a.f;
}
__device__ __forceinline__ float gelu_fast(float h) {
  // 0.5h(1+tanh(u)) = h*sigmoid(2u); 2u*log2e = h*(2.3022082+0.1029471h^2)
  float h2 = h * h;
  float w  = h * (2.3022082f + 0.1029471f * h2);
  float e  = __builtin_amdgcn_exp2f(w);
  float r  = __builtin_amdgcn_rcpf(e + 1.0f);
  return h - h * r;
}

// ws layout (bytes):
//   WcT  [128][384]s @0       (98304)   row n (DIN), k-major; g1-folded
//   W1Ta [256][128]s @98304   (65536)   W1[k][n]*g2[k], n<256
//   W2Ta [4][128][64]s @163840 (65536)
//   W1Tb [256][128]s @229376  (65536)
//   W2Tb [4][128][64]s @294912 (65536)
//   bc   [128]f32 @360448     bp + (bkv_v + b1@Wv)@Wp
//   bm1c [512]f32 @360960     bm1 + b2@W1
//   css  [128]f32 @363008     colsum of bf16 WcT (csscalc kernel)

// ---------------- prep (707 blocks x 256) ------------------------------------
__global__ void prep(const float* __restrict__ Wkv, const float* __restrict__ bkv,
                     const float* __restrict__ Wp,  const float* __restrict__ bp,
                     const float* __restrict__ W1,  const float* __restrict__ W2,
                     const float* __restrict__ g1,  const float* __restrict__ b1,
                     const float* __restrict__ g2,  const float* __restrict__ b2,
                     const float* __restrict__ bm1,
                     short* __restrict__ WcT, short* __restrict__ W1Ta,
                     short* __restrict__ W1Tb, short* __restrict__ W2Ta,
                     short* __restrict__ W2Tb, float* __restrict__ bc,
                     float* __restrict__ bm1c) {
  const int b = blockIdx.x, tid = threadIdx.x;
  if (b < 192) {                        // WcT fold + g1 scale
    __shared__ float wv[2][128];
    const int kk = tid >> 7, n = tid & 127, k = 2 * b + kk;
    wv[kk][n] = Wkv[k * 256 + 128 + n];
    __syncthreads();
    float s0 = 0, s1 = 0, s2 = 0, s3 = 0;
#pragma unroll 8
    for (int m = 0; m < 128; m += 4) {
      s0 += wv[kk][m]     * Wp[(m)     * 128 + n];
      s1 += wv[kk][m + 1] * Wp[(m + 1) * 128 + n];
      s2 += wv[kk][m + 2] * Wp[(m + 2) * 128 + n];
      s3 += wv[kk][m + 3] * Wp[(m + 3) * 128 + n];
    }
    WcT[n * 384 + k] = f2bf(g1[k] * (s0 + s1 + s2 + s3));
  } else if (b == 192) {                // bc = bp + (bkv_v + b1@Wv)@Wp
    __shared__ float t[128];
    if (tid < 128) {
      float a0 = 0, a1 = 0, a2 = 0, a3 = 0;
#pragma unroll 8
      for (int k = 0; k < 384; k += 4) {
        a0 += b1[k]     * Wkv[(k)     * 256 + 128 + tid];
        a1 += b1[k + 1] * Wkv[(k + 1) * 256 + 128 + tid];
        a2 += b1[k + 2] * Wkv[(k + 2) * 256 + 128 + tid];
        a3 += b1[k + 3] * Wkv[(k + 3) * 256 + 128 + tid];
      }
      t[tid] = a0 + a1 + a2 + a3 + bkv[128 + tid];
    }
    __syncthreads();
    if (tid < 128) {
      float s = bp[tid];
#pragma unroll 8
      for (int m = 0; m < 128; ++m) s += t[m] * Wp[m * 128 + tid];
      bc[tid] = s;
    }
  } else if (b < 449) {                 // W1T halves, rows scaled by g2[k]
    const int id = (b - 193) * 256 + tid;
    const int n = id & 511, k = id >> 9;
    const short v = f2bf(W1[k * 512 + n] * g2[k]);
    if (n < 256) W1Ta[n * 128 + k] = v;
    else         W1Tb[(n - 256) * 128 + k] = v;
  } else if (b < 705) {                 // W2T, ch-chunked halves
    const int id = (b - 449) * 256 + tid;
    const int n = id & 127, k = id >> 7;
    const int ch = k >> 6, kk = k & 63;
    short* dst = (ch < 4) ? W2Ta : W2Tb;
    dst[((ch & 3) * 128 + n) * 64 + kk] = f2bf(W2[k * 128 + n]);
  } else {                              // bm1c = bm1 + b2@W1
    const int h = (b - 705) * 256 + tid;   // [0,512)
    float s = bm1[h];
#pragma unroll 8
    for (int k = 0; k < 128; ++k) s += b2[k] * W1[k * 512 + h];
    bm1c[h] = s;
  }
}

// ---------------- csscalc: colsum of the exact bf16 weights (1 x 128) --------
__global__ void csscalc(const short* __restrict__ WcT, float* __restrict__ css) {
  const int n = threadIdx.x;            // [0,128)
  const short* row = WcT + n * 384;
  float s = 0.f;
#pragma unroll
  for (int k = 0; k < 384; k += 8) {
    bf16x8 v = *(const bf16x8*)(row + k);
#pragma unroll
    for (int j = 0; j < 8; ++j) s += bf2f(v[j]);
  }
  css[n] = s;
}

// ---------------- fused: LN1@Wc + LN2 + MLP, no LDS staging, no barriers -----
__global__ __launch_bounds__(256)
void fused(const float* __restrict__ x, const short* __restrict__ WcTg,
           const float* __restrict__ bcg, const float* __restrict__ cssg,
           const short* __restrict__ W1Tag, const short* __restrict__ W2Tag,
           const short* __restrict__ W1Tbg, const short* __restrict__ W2Tbg,
           const float* __restrict__ bm1c, const float* __restrict__ bm2g,
           float* __restrict__ out) {
  __shared__ __align__(16) short A3s[4][576];   // per-wave scratch only
  const int tid = threadIdx.x, lane = tid & 63, w = tid >> 6;
  const int q = lane >> 4, c16 = lane & 15;
  const long band = (long)blockIdx.x * 4 + w;
  const float* xp = x + (band * 16 + c16) * 384 + q * 8;

  // ---- phase 1: y = LN1(x)@Wc + bc via linearity; B-frags from L2
  f32x4 yacc[8];
#pragma unroll
  for (int t = 0; t < 8; ++t) yacc[t] = (f32x4){0.f, 0.f, 0.f, 0.f};
  float s = 0.f, sq = 0.f;
#pragma unroll
  for (int ks = 0; ks < 12; ++ks) {
    const float4 va = *(const float4*)(xp + ks * 32);
    const float4 vb = *(const float4*)(xp + ks * 32 + 4);
    s  += va.x + va.y + va.z + va.w + vb.x + vb.y + vb.z + vb.w;
    sq += va.x * va.x + va.y * va.y + va.z * va.z + va.w * va.w
        + vb.x * vb.x + vb.y * vb.y + vb.z * vb.z + vb.w * vb.w;
    bf16x8 f;
    f[0] = f2bf(va.x); f[1] = f2bf(va.y); f[2] = f2bf(va.z); f[3] = f2bf(va.w);
    f[4] = f2bf(vb.x); f[5] = f2bf(vb.y); f[6] = f2bf(vb.z); f[7] = f2bf(vb.w);
#pragma unroll
    for (int t = 0; t < 8; ++t) {
      bf16x8 bfr = *(const bf16x8*)(WcTg + (t * 16 + c16) * 384 + ks * 32 + q * 8);
      yacc[t] = __builtin_amdgcn_mfma_f32_16x16x32_bf16(f, bfr, yacc[t], 0, 0, 0);
    }
  }
  // LN1 stats
  s  += __shfl_xor(s, 16);  s  += __shfl_xor(s, 32);
  sq += __shfl_xor(sq, 16); sq += __shfl_xor(sq, 32);
  const float mean = s * (1.f / 384.f);
  const float rs = rsqrtf(sq * (1.f / 384.f) - mean * mean + 1e-5f);
  float mr[4], rr[4];
#pragma unroll
  for (int r = 0; r < 4; ++r) {
    mr[r] = __shfl(mean, q * 4 + r);
    rr[r] = __shfl(rs,   q * 4 + r);
  }

  // ---- finalize y = rr*(u - mr*colsum) + bc; LN2 stats (css/bc from L2)
  float sm[4] = {0, 0, 0, 0}, sv[4] = {0, 0, 0, 0};
#pragma unroll
  for (int t = 0; t < 8; ++t) {
    const float cst = cssg[t * 16 + c16];
    const float bct = bcg[t * 16 + c16];
#pragma unroll
    for (int r = 0; r < 4; ++r) {
      const float yv = rr[r] * (yacc[t][r] - mr[r] * cst) + bct;
      yacc[t][r] = yv; sm[r] += yv; sv[r] += yv * yv;
    }
  }
#pragma unroll
  for (int r = 0; r < 4; ++r) {
    sm[r] += __shfl_xor(sm[r], 1); sm[r] += __shfl_xor(sm[r], 2);
    sm[r] += __shfl_xor(sm[r], 4); sm[r] += __shfl_xor(sm[r], 8);
    sv[r] += __shfl_xor(sv[r], 1); sv[r] += __shfl_xor(sv[r], 2);
    sv[r] += __shfl_xor(sv[r], 4); sv[r] += __shfl_xor(sv[r], 8);
  }
  float mn[4], rv[4];
#pragma unroll
  for (int r = 0; r < 4; ++r) {
    mn[r] = sm[r] * (1.f / 128.f);
    rv[r] = rsqrtf(sv[r] * (1.f / 128.f) - mn[r] * mn[r] + 1e-5f);
  }

  // ---- bounce y-norm (g2/b2 folded) -> A-fragments via per-wave LDS chunk
  short* A3w = A3s[w];
  bf16x8 a2f[4];
#pragma unroll
  for (int ks = 0; ks < 4; ++ks) {
#pragma unroll
    for (int tt = 0; tt < 2; ++tt) {
      const int t = ks * 2 + tt;
#pragma unroll
      for (int r = 0; r < 4; ++r)
        A3w[tt * 256 + r * 64 + q * 16 + c16] = f2bf((yacc[t][r] - mn[r]) * rv[r]);
    }
    asm volatile("s_waitcnt lgkmcnt(0)" ::: "memory");  // in-wave RAW
    a2f[ks] = *(const bf16x8*)(A3w + (q >> 1) * 256 + (c16 & 3) * 64 +
                               (c16 >> 2) * 16 + (q & 1) * 8);
  }

  // ---- fold y (+bm2) into the MLP accumulator; yacc dies here
  f32x4 zacc[8];
#pragma unroll
  for (int t = 0; t < 8; ++t) {
    const float bb2 = bm2g[t * 16 + c16];
#pragma unroll
    for (int r = 0; r < 4; ++r) zacc[t][r] = yacc[t][r] + bb2;
  }

  // ---- phase 2: MLP, both hidden halves; W1/W2 frags straight from L2
#pragma unroll
  for (int half = 0; half < 2; ++half) {
    const short* W1g = half ? W1Tbg : W1Tag;
    const short* W2g = half ? W2Tbg : W2Tag;
#pragma unroll
    for (int ch = 0; ch < 4; ++ch) {
#pragma unroll
      for (int sub = 0; sub < 2; ++sub) {
        f32x4 hacc[2];
        hacc[0] = (f32x4){0.f, 0.f, 0.f, 0.f};
        hacc[1] = (f32x4){0.f, 0.f, 0.f, 0.f};
#pragma unroll
        for (int ks = 0; ks < 4; ++ks)
#pragma unroll
          for (int tt = 0; tt < 2; ++tt) {
            bf16x8 bfr = *(const bf16x8*)(W1g + (ch * 64 + sub * 32 + tt * 16 + c16) * 128 + ks * 32 + q * 8);
            hacc[tt] = __builtin_amdgcn_mfma_f32_16x16x32_bf16(a2f[ks], bfr, hacc[tt], 0, 0, 0);
          }
#pragma unroll
        for (int tt = 0; tt < 2; ++tt) {
          const float bb = bm1c[half * 256 + ch * 64 + sub * 32 + tt * 16 + c16];
#pragma unroll
          for (int r = 0; r < 4; ++r) {
            const float h = hacc[tt][r] + bb;
            A3w[(q * 4 + r) * 36 + tt * 16 + c16] = f2bf(gelu_fast(h));
          }
        }
        asm volatile("s_waitcnt lgkmcnt(0)" ::: "memory");  // in-wave A3 RAW
        bf16x8 af = *(const bf16x8*)(A3w + c16 * 36 + q * 8);
#pragma unroll
        for (int t = 0; t < 8; ++t) {
          bf16x8 bfr = *(const bf16x8*)(W2g + (ch * 128 + t * 16 + c16) * 64 + sub * 32 + q * 8);
          zacc[t] = __builtin_amdgcn_mfma_f32_16x16x32_bf16(af, bfr, zacc[t], 0, 0, 0);
        }
      }
    }
  }

  // ---- epilogue: out = zacc (= y + mlp + bm2, all f32)
#pragma unroll
  for (int r = 0; r < 4; ++r) {
    const long rowg = band * 16 + q * 4 + r;
#pragma unroll
    for (int t = 0; t < 8; ++t)
      out[rowg * 128 + t * 16 + c16] = zacc[t][r];
  }
}

extern "C" void kernel_launch(void* const* d_in, const int* in_sizes, int n_in,
                              void* d_out, int out_size, void* d_ws, size_t ws_size,
                              hipStream_t stream) {
  const float* x   = (const float*)d_in[0];
  const float* g1  = (const float*)d_in[1];
  const float* b1  = (const float*)d_in[2];
  // d_in[3]=Wq, [4]=bq, [7]=rpb dead (softmax over size-1 axis == 1)
  const float* Wkv = (const float*)d_in[5];
  const float* bkv = (const float*)d_in[6];
  const float* Wp  = (const float*)d_in[8];
  const float* bp  = (const float*)d_in[9];
  const float* g2  = (const float*)d_in[10];
  const float* b2  = (const float*)d_in[11];
  const float* W1  = (const float*)d_in[12];
  const float* bm1 = (const float*)d_in[13];
  const float* W2  = (const float*)d_in[14];
  const float* bm2 = (const float*)d_in[15];

  char* ws = (char*)d_ws;
  short* WcT  = (short*)(ws + 0);
  short* W1Ta = (short*)(ws + 98304);
  short* W2Ta = (short*)(ws + 163840);
  short* W1Tb = (short*)(ws + 229376);
  short* W2Tb = (short*)(ws + 294912);
  float* bc   = (float*)(ws + 360448);
  float* bm1c = (float*)(ws + 360960);
  float* css  = (float*)(ws + 363008);

  prep<<<707, 256, 0, stream>>>(Wkv, bkv, Wp, bp, W1, W2, g1, b1, g2, b2, bm1,
                                WcT, W1Ta, W1Tb, W2Ta, W2Tb, bc, bm1c);
  csscalc<<<1, 128, 0, stream>>>(WcT, css);
  fused<<<1024, 256, 0, stream>>>(x, WcT, bc, css, W1Ta, W2Ta, W1Tb, W2Tb,
                                  bm1c, bm2, (float*)d_out);
}

// Round 8
// 290.158 us; speedup vs baseline: 1.1817x; 1.1817x over previous
//
#include <hip/hip_runtime.h>
#include <hip/hip_bf16.h>
#include <stdint.h>

// B=8 L=8192 C=384 DIN=128 HID=512, tokens=65536, bands(16 tok)=4096.
// softmax over size-1 axis == 1 -> attention out == v -> fold Wc = Wv@Wp.
// z = y + gelu(LN2(y)@W1+bm1)@W2 + bm2,  y = LN1(x)@Wc + bc.
// R13: R12 cleaned spills (VGPR 108, WRITE=logical) but time pinned at 190us
// with everything idle -> binding resource is L2/L3 weight re-fetch:
// 4096 waves x 352KB = 1.44GB/dispatch ~ 7.6TB/s. Lever: M=32 tokens/wave
// (2 bands) so every B-fragment load feeds 2 MFMAs -> re-fetch halves to
// 0.74GB. Affordable only now that 256-thr blocks lift the 64-reg ceiling
// (phase2 live ~170 regs). Still zero barriers, grid 512x256.
// csscalc widened 1 block -> 128 blocks (1-block kernel = 1 CU serial tail).

typedef __attribute__((ext_vector_type(8))) short bf16x8;
typedef __attribute__((ext_vector_type(4))) float f32x4;

__device__ __forceinline__ short f2bf(float f) {
  union { float f; unsigned u; } a; a.f = f;
  unsigned u = a.u;
  u += 0x7fffu + ((u >> 16) & 1u);   // RNE, finite inputs
  return (short)(u >> 16);
}
__device__ __forceinline__ float bf2f(short s) {
  union { unsigned u; float f; } a; a.u = ((unsigned)(unsigned short)s) << 16;
  return a.f;
}
__device__ __forceinline__ float gelu_fast(float h) {
  // 0.5h(1+tanh(u)) = h*sigmoid(2u); 2u*log2e = h*(2.3022082+0.1029471h^2)
  float h2 = h * h;
  float w  = h * (2.3022082f + 0.1029471f * h2);
  float e  = __builtin_amdgcn_exp2f(w);
  float r  = __builtin_amdgcn_rcpf(e + 1.0f);
  return h - h * r;
}

// ws layout (bytes):
//   WcT  [128][384]s @0       (98304)   row n (DIN), k-major; g1-folded
//   W1Ta [256][128]s @98304   (65536)   W1[k][n]*g2[k], n<256
//   W2Ta [4][128][64]s @163840 (65536)
//   W1Tb [256][128]s @229376  (65536)
//   W2Tb [4][128][64]s @294912 (65536)
//   bc   [128]f32 @360448     bp + (bkv_v + b1@Wv)@Wp
//   bm1c [512]f32 @360960     bm1 + b2@W1
//   css  [128]f32 @363008     colsum of bf16 WcT (csscalc kernel)

// ---------------- prep (707 blocks x 256) ------------------------------------
__global__ void prep(const float* __restrict__ Wkv, const float* __restrict__ bkv,
                     const float* __restrict__ Wp,  const float* __restrict__ bp,
                     const float* __restrict__ W1,  const float* __restrict__ W2,
                     const float* __restrict__ g1,  const float* __restrict__ b1,
                     const float* __restrict__ g2,  const float* __restrict__ b2,
                     const float* __restrict__ bm1,
                     short* __restrict__ WcT, short* __restrict__ W1Ta,
                     short* __restrict__ W1Tb, short* __restrict__ W2Ta,
                     short* __restrict__ W2Tb, float* __restrict__ bc,
                     float* __restrict__ bm1c) {
  const int b = blockIdx.x, tid = threadIdx.x;
  if (b < 192) {                        // WcT fold + g1 scale
    __shared__ float wv[2][128];
    const int kk = tid >> 7, n = tid & 127, k = 2 * b + kk;
    wv[kk][n] = Wkv[k * 256 + 128 + n];
    __syncthreads();
    float s0 = 0, s1 = 0, s2 = 0, s3 = 0;
#pragma unroll 8
    for (int m = 0; m < 128; m += 4) {
      s0 += wv[kk][m]     * Wp[(m)     * 128 + n];
      s1 += wv[kk][m + 1] * Wp[(m + 1) * 128 + n];
      s2 += wv[kk][m + 2] * Wp[(m + 2) * 128 + n];
      s3 += wv[kk][m + 3] * Wp[(m + 3) * 128 + n];
    }
    WcT[n * 384 + k] = f2bf(g1[k] * (s0 + s1 + s2 + s3));
  } else if (b == 192) {                // bc = bp + (bkv_v + b1@Wv)@Wp
    __shared__ float t[128];
    if (tid < 128) {
      float a0 = 0, a1 = 0, a2 = 0, a3 = 0;
#pragma unroll 8
      for (int k = 0; k < 384; k += 4) {
        a0 += b1[k]     * Wkv[(k)     * 256 + 128 + tid];
        a1 += b1[k + 1] * Wkv[(k + 1) * 256 + 128 + tid];
        a2 += b1[k + 2] * Wkv[(k + 2) * 256 + 128 + tid];
        a3 += b1[k + 3] * Wkv[(k + 3) * 256 + 128 + tid];
      }
      t[tid] = a0 + a1 + a2 + a3 + bkv[128 + tid];
    }
    __syncthreads();
    if (tid < 128) {
      float s = bp[tid];
#pragma unroll 8
      for (int m = 0; m < 128; ++m) s += t[m] * Wp[m * 128 + tid];
      bc[tid] = s;
    }
  } else if (b < 449) {                 // W1T halves, rows scaled by g2[k]
    const int id = (b - 193) * 256 + tid;
    const int n = id & 511, k = id >> 9;
    const short v = f2bf(W1[k * 512 + n] * g2[k]);
    if (n < 256) W1Ta[n * 128 + k] = v;
    else         W1Tb[(n - 256) * 128 + k] = v;
  } else if (b < 705) {                 // W2T, ch-chunked halves
    const int id = (b - 449) * 256 + tid;
    const int n = id & 127, k = id >> 7;
    const int ch = k >> 6, kk = k & 63;
    short* dst = (ch < 4) ? W2Ta : W2Tb;
    dst[((ch & 3) * 128 + n) * 64 + kk] = f2bf(W2[k * 128 + n]);
  } else {                              // bm1c = bm1 + b2@W1
    const int h = (b - 705) * 256 + tid;   // [0,512)
    float s = bm1[h];
#pragma unroll 8
    for (int k = 0; k < 128; ++k) s += b2[k] * W1[k * 512 + h];
    bm1c[h] = s;
  }
}

// ---------------- csscalc: colsum of the bf16 WcT (128 blocks x 64) ----------
__global__ void csscalc(const short* __restrict__ WcT, float* __restrict__ css) {
  const int n = blockIdx.x;             // [0,128)
  const int lane = threadIdx.x;         // [0,64)
  float s = 0.f;
  if (lane < 48) {
    bf16x8 v = *(const bf16x8*)(WcT + n * 384 + lane * 8);
#pragma unroll
    for (int j = 0; j < 8; ++j) s += bf2f(v[j]);
  }
  s += __shfl_xor(s, 1);  s += __shfl_xor(s, 2);  s += __shfl_xor(s, 4);
  s += __shfl_xor(s, 8);  s += __shfl_xor(s, 16); s += __shfl_xor(s, 32);
  if (lane == 0) css[n] = s;
}

// ---------------- fused: LN1@Wc + LN2 + MLP, M=32/wave, no barriers ----------
__global__ __launch_bounds__(256)
void fused(const float* __restrict__ x, const short* __restrict__ WcTg,
           const float* __restrict__ bcg, const float* __restrict__ cssg,
           const short* __restrict__ W1Tag, const short* __restrict__ W2Tag,
           const short* __restrict__ W1Tbg, const short* __restrict__ W2Tbg,
           const float* __restrict__ bm1c, const float* __restrict__ bm2g,
           float* __restrict__ out) {
  __shared__ __align__(16) short A3s[4][1152];  // per-wave, 576 per band
  const int tid = threadIdx.x, lane = tid & 63, w = tid >> 6;
  const int q = lane >> 4, c16 = lane & 15;
  const long band0 = (long)blockIdx.x * 8 + w * 2;  // wave owns bands band0, band0+1
  const float* xp0 = x + (band0 * 16 + c16) * 384 + q * 8;
  const float* xp1 = xp0 + 16 * 384;

  // ---- phase 1: y = LN1(x)@Wc + bc via linearity; each bfr feeds 2 MFMAs
  f32x4 yacc[2][8];
#pragma unroll
  for (int m = 0; m < 2; ++m)
#pragma unroll
    for (int t = 0; t < 8; ++t) yacc[m][t] = (f32x4){0.f, 0.f, 0.f, 0.f};
  float s0 = 0.f, sq0 = 0.f, s1 = 0.f, sq1 = 0.f;
#pragma unroll
  for (int ks = 0; ks < 12; ++ks) {
    const float4 va0 = *(const float4*)(xp0 + ks * 32);
    const float4 vb0 = *(const float4*)(xp0 + ks * 32 + 4);
    const float4 va1 = *(const float4*)(xp1 + ks * 32);
    const float4 vb1 = *(const float4*)(xp1 + ks * 32 + 4);
    s0  += va0.x + va0.y + va0.z + va0.w + vb0.x + vb0.y + vb0.z + vb0.w;
    sq0 += va0.x * va0.x + va0.y * va0.y + va0.z * va0.z + va0.w * va0.w
         + vb0.x * vb0.x + vb0.y * vb0.y + vb0.z * vb0.z + vb0.w * vb0.w;
    s1  += va1.x + va1.y + va1.z + va1.w + vb1.x + vb1.y + vb1.z + vb1.w;
    sq1 += va1.x * va1.x + va1.y * va1.y + va1.z * va1.z + va1.w * va1.w
         + vb1.x * vb1.x + vb1.y * vb1.y + vb1.z * vb1.z + vb1.w * vb1.w;
    bf16x8 f0, f1;
    f0[0] = f2bf(va0.x); f0[1] = f2bf(va0.y); f0[2] = f2bf(va0.z); f0[3] = f2bf(va0.w);
    f0[4] = f2bf(vb0.x); f0[5] = f2bf(vb0.y); f0[6] = f2bf(vb0.z); f0[7] = f2bf(vb0.w);
    f1[0] = f2bf(va1.x); f1[1] = f2bf(va1.y); f1[2] = f2bf(va1.z); f1[3] = f2bf(va1.w);
    f1[4] = f2bf(vb1.x); f1[5] = f2bf(vb1.y); f1[6] = f2bf(vb1.z); f1[7] = f2bf(vb1.w);
#pragma unroll
    for (int t = 0; t < 8; ++t) {
      bf16x8 bfr = *(const bf16x8*)(WcTg + (t * 16 + c16) * 384 + ks * 32 + q * 8);
      yacc[0][t] = __builtin_amdgcn_mfma_f32_16x16x32_bf16(f0, bfr, yacc[0][t], 0, 0, 0);
      yacc[1][t] = __builtin_amdgcn_mfma_f32_16x16x32_bf16(f1, bfr, yacc[1][t], 0, 0, 0);
    }
  }
  // LN1 stats per band
  s0  += __shfl_xor(s0, 16);  s0  += __shfl_xor(s0, 32);
  sq0 += __shfl_xor(sq0, 16); sq0 += __shfl_xor(sq0, 32);
  s1  += __shfl_xor(s1, 16);  s1  += __shfl_xor(s1, 32);
  sq1 += __shfl_xor(sq1, 16); sq1 += __shfl_xor(sq1, 32);
  const float mean0 = s0 * (1.f / 384.f);
  const float rs0 = rsqrtf(sq0 * (1.f / 384.f) - mean0 * mean0 + 1e-5f);
  const float mean1 = s1 * (1.f / 384.f);
  const float rs1 = rsqrtf(sq1 * (1.f / 384.f) - mean1 * mean1 + 1e-5f);
  float mr[2][4], rr[2][4];
#pragma unroll
  for (int r = 0; r < 4; ++r) {
    mr[0][r] = __shfl(mean0, q * 4 + r);
    rr[0][r] = __shfl(rs0,   q * 4 + r);
    mr[1][r] = __shfl(mean1, q * 4 + r);
    rr[1][r] = __shfl(rs1,   q * 4 + r);
  }

  // ---- finalize y = rr*(u - mr*colsum) + bc; LN2 stats
  float sm[2][4] = {{0,0,0,0},{0,0,0,0}}, sv[2][4] = {{0,0,0,0},{0,0,0,0}};
#pragma unroll
  for (int t = 0; t < 8; ++t) {
    const float cst = cssg[t * 16 + c16];
    const float bct = bcg[t * 16 + c16];
#pragma unroll
    for (int m = 0; m < 2; ++m)
#pragma unroll
      for (int r = 0; r < 4; ++r) {
        const float yv = rr[m][r] * (yacc[m][t][r] - mr[m][r] * cst) + bct;
        yacc[m][t][r] = yv; sm[m][r] += yv; sv[m][r] += yv * yv;
      }
  }
  float mn[2][4], rv[2][4];
#pragma unroll
  for (int m = 0; m < 2; ++m)
#pragma unroll
    for (int r = 0; r < 4; ++r) {
      sm[m][r] += __shfl_xor(sm[m][r], 1); sm[m][r] += __shfl_xor(sm[m][r], 2);
      sm[m][r] += __shfl_xor(sm[m][r], 4); sm[m][r] += __shfl_xor(sm[m][r], 8);
      sv[m][r] += __shfl_xor(sv[m][r], 1); sv[m][r] += __shfl_xor(sv[m][r], 2);
      sv[m][r] += __shfl_xor(sv[m][r], 4); sv[m][r] += __shfl_xor(sv[m][r], 8);
      mn[m][r] = sm[m][r] * (1.f / 128.f);
      rv[m][r] = rsqrtf(sv[m][r] * (1.f / 128.f) - mn[m][r] * mn[m][r] + 1e-5f);
    }

  // ---- bounce y-norm (g2/b2 folded) -> A-fragments, per band (own 576 half)
  short* A3w = A3s[w];
  bf16x8 a2f[2][4];
#pragma unroll
  for (int m = 0; m < 2; ++m)
#pragma unroll
    for (int ks = 0; ks < 4; ++ks) {
#pragma unroll
      for (int tt = 0; tt < 2; ++tt) {
        const int t = ks * 2 + tt;
#pragma unroll
        for (int r = 0; r < 4; ++r)
          A3w[m * 576 + tt * 256 + r * 64 + q * 16 + c16] =
              f2bf((yacc[m][t][r] - mn[m][r]) * rv[m][r]);
      }
      asm volatile("s_waitcnt lgkmcnt(0)" ::: "memory");  // in-wave RAW
      a2f[m][ks] = *(const bf16x8*)(A3w + m * 576 + (q >> 1) * 256 +
                                    (c16 & 3) * 64 + (c16 >> 2) * 16 + (q & 1) * 8);
    }

  // ---- fold y (+bm2) into the MLP accumulator; yacc dies here
  f32x4 zacc[2][8];
#pragma unroll
  for (int t = 0; t < 8; ++t) {
    const float bb2 = bm2g[t * 16 + c16];
#pragma unroll
    for (int m = 0; m < 2; ++m)
#pragma unroll
      for (int r = 0; r < 4; ++r) zacc[m][t][r] = yacc[m][t][r] + bb2;
  }

  // ---- phase 2: MLP; every W1/W2 fragment feeds 2 MFMAs
#pragma unroll
  for (int half = 0; half < 2; ++half) {
    const short* W1g = half ? W1Tbg : W1Tag;
    const short* W2g = half ? W2Tbg : W2Tag;
#pragma unroll
    for (int ch = 0; ch < 4; ++ch) {
#pragma unroll
      for (int sub = 0; sub < 2; ++sub) {
        f32x4 hacc[2][2];
        hacc[0][0] = (f32x4){0.f,0.f,0.f,0.f}; hacc[0][1] = (f32x4){0.f,0.f,0.f,0.f};
        hacc[1][0] = (f32x4){0.f,0.f,0.f,0.f}; hacc[1][1] = (f32x4){0.f,0.f,0.f,0.f};
#pragma unroll
        for (int ks = 0; ks < 4; ++ks)
#pragma unroll
          for (int tt = 0; tt < 2; ++tt) {
            bf16x8 bfr = *(const bf16x8*)(W1g + (ch * 64 + sub * 32 + tt * 16 + c16) * 128 + ks * 32 + q * 8);
            hacc[0][tt] = __builtin_amdgcn_mfma_f32_16x16x32_bf16(a2f[0][ks], bfr, hacc[0][tt], 0, 0, 0);
            hacc[1][tt] = __builtin_amdgcn_mfma_f32_16x16x32_bf16(a2f[1][ks], bfr, hacc[1][tt], 0, 0, 0);
          }
#pragma unroll
        for (int m = 0; m < 2; ++m)
#pragma unroll
          for (int tt = 0; tt < 2; ++tt) {
            const float bb = bm1c[half * 256 + ch * 64 + sub * 32 + tt * 16 + c16];
#pragma unroll
            for (int r = 0; r < 4; ++r) {
              const float h = hacc[m][tt][r] + bb;
              A3w[m * 576 + (q * 4 + r) * 36 + tt * 16 + c16] = f2bf(gelu_fast(h));
            }
          }
        asm volatile("s_waitcnt lgkmcnt(0)" ::: "memory");  // in-wave A3 RAW
        bf16x8 af0 = *(const bf16x8*)(A3w + c16 * 36 + q * 8);
        bf16x8 af1 = *(const bf16x8*)(A3w + 576 + c16 * 36 + q * 8);
#pragma unroll
        for (int t = 0; t < 8; ++t) {
          bf16x8 bfr = *(const bf16x8*)(W2g + (ch * 128 + t * 16 + c16) * 64 + sub * 32 + q * 8);
          zacc[0][t] = __builtin_amdgcn_mfma_f32_16x16x32_bf16(af0, bfr, zacc[0][t], 0, 0, 0);
          zacc[1][t] = __builtin_amdgcn_mfma_f32_16x16x32_bf16(af1, bfr, zacc[1][t], 0, 0, 0);
        }
      }
    }
  }

  // ---- epilogue: out = zacc (= y + mlp + bm2, all f32)
#pragma unroll
  for (int m = 0; m < 2; ++m)
#pragma unroll
    for (int r = 0; r < 4; ++r) {
      const long rowg = (band0 + m) * 16 + q * 4 + r;
#pragma unroll
      for (int t = 0; t < 8; ++t)
        out[rowg * 128 + t * 16 + c16] = zacc[m][t][r];
    }
}

extern "C" void kernel_launch(void* const* d_in, const int* in_sizes, int n_in,
                              void* d_out, int out_size, void* d_ws, size_t ws_size,
                              hipStream_t stream) {
  const float* x   = (const float*)d_in[0];
  const float* g1  = (const float*)d_in[1];
  const float* b1  = (const float*)d_in[2];
  // d_in[3]=Wq, [4]=bq, [7]=rpb dead (softmax over size-1 axis == 1)
  const float* Wkv = (const float*)d_in[5];
  const float* bkv = (const float*)d_in[6];
  const float* Wp  = (const float*)d_in[8];
  const float* bp  = (const float*)d_in[9];
  const float* g2  = (const float*)d_in[10];
  const float* b2  = (const float*)d_in[11];
  const float* W1  = (const float*)d_in[12];
  const float* bm1 = (const float*)d_in[13];
  const float* W2  = (const float*)d_in[14];
  const float* bm2 = (const float*)d_in[15];

  char* ws = (char*)d_ws;
  short* WcT  = (short*)(ws + 0);
  short* W1Ta = (short*)(ws + 98304);
  short* W2Ta = (short*)(ws + 163840);
  short* W1Tb = (short*)(ws + 229376);
  short* W2Tb = (short*)(ws + 294912);
  float* bc   = (float*)(ws + 360448);
  float* bm1c = (float*)(ws + 360960);
  float* css  = (float*)(ws + 363008);

  prep<<<707, 256, 0, stream>>>(Wkv, bkv, Wp, bp, W1, W2, g1, b1, g2, b2, bm1,
                                WcT, W1Ta, W1Tb, W2Ta, W2Tb, bc, bm1c);
  csscalc<<<128, 64, 0, stream>>>(WcT, css);
  fused<<<512, 256, 0, stream>>>(x, WcT, bc, css, W1Ta, W2Ta, W1Tb, W2Tb,
                                 bm1c, bm2, (float*)d_out);
}

// Round 9
// 284.576 us; speedup vs baseline: 1.2049x; 1.0196x over previous
//
#include <hip/hip_runtime.h>
#include <hip/hip_bf16.h>
#include <stdint.h>

// B=8 L=8192 C=384 DIN=128 HID=512, tokens=65536, bands(16 tok)=4096.
// softmax over size-1 axis == 1 -> attention out == v -> fold Wc = Wv@Wp.
// z = y + gelu(LN2(y)@W1+bm1)@W2 + bm2,  y = LN1(x)@Wc + bc.
// R14: R13 + fence removal. The 24 asm lgkmcnt(0) fences carried a "memory"
// clobber = full compiler barrier -> W2's 256 fragment loads/wave (and the
// a2f bounce reads) could never hoist above the gelu/LDS sections; ~16 naked
// L2 round-trips per wave. LDS RAW within a wave is safe without them:
// ops are compiler-visible, alias-ordered, DS executes in order, and the
// compiler auto-inserts lgkmcnt before dependent uses. Also explicitly
// preload the 8 W2 frags per sub-iter BEFORE gelu (guaranteed overlap).

typedef __attribute__((ext_vector_type(8))) short bf16x8;
typedef __attribute__((ext_vector_type(4))) float f32x4;

__device__ __forceinline__ short f2bf(float f) {
  union { float f; unsigned u; } a; a.f = f;
  unsigned u = a.u;
  u += 0x7fffu + ((u >> 16) & 1u);   // RNE, finite inputs
  return (short)(u >> 16);
}
__device__ __forceinline__ float bf2f(short s) {
  union { unsigned u; float f; } a; a.u = ((unsigned)(unsigned short)s) << 16;
  return a.f;
}
__device__ __forceinline__ float gelu_fast(float h) {
  // 0.5h(1+tanh(u)) = h*sigmoid(2u); 2u*log2e = h*(2.3022082+0.1029471h^2)
  float h2 = h * h;
  float w  = h * (2.3022082f + 0.1029471f * h2);
  float e  = __builtin_amdgcn_exp2f(w);
  float r  = __builtin_amdgcn_rcpf(e + 1.0f);
  return h - h * r;
}

// ws layout (bytes):
//   WcT  [128][384]s @0       (98304)   row n (DIN), k-major; g1-folded
//   W1Ta [256][128]s @98304   (65536)   W1[k][n]*g2[k], n<256
//   W2Ta [4][128][64]s @163840 (65536)
//   W1Tb [256][128]s @229376  (65536)
//   W2Tb [4][128][64]s @294912 (65536)
//   bc   [128]f32 @360448     bp + (bkv_v + b1@Wv)@Wp
//   bm1c [512]f32 @360960     bm1 + b2@W1
//   css  [128]f32 @363008     colsum of bf16 WcT (csscalc kernel)

// ---------------- prep (707 blocks x 256) ------------------------------------
__global__ void prep(const float* __restrict__ Wkv, const float* __restrict__ bkv,
                     const float* __restrict__ Wp,  const float* __restrict__ bp,
                     const float* __restrict__ W1,  const float* __restrict__ W2,
                     const float* __restrict__ g1,  const float* __restrict__ b1,
                     const float* __restrict__ g2,  const float* __restrict__ b2,
                     const float* __restrict__ bm1,
                     short* __restrict__ WcT, short* __restrict__ W1Ta,
                     short* __restrict__ W1Tb, short* __restrict__ W2Ta,
                     short* __restrict__ W2Tb, float* __restrict__ bc,
                     float* __restrict__ bm1c) {
  const int b = blockIdx.x, tid = threadIdx.x;
  if (b < 192) {                        // WcT fold + g1 scale
    __shared__ float wv[2][128];
    const int kk = tid >> 7, n = tid & 127, k = 2 * b + kk;
    wv[kk][n] = Wkv[k * 256 + 128 + n];
    __syncthreads();
    float s0 = 0, s1 = 0, s2 = 0, s3 = 0;
#pragma unroll 8
    for (int m = 0; m < 128; m += 4) {
      s0 += wv[kk][m]     * Wp[(m)     * 128 + n];
      s1 += wv[kk][m + 1] * Wp[(m + 1) * 128 + n];
      s2 += wv[kk][m + 2] * Wp[(m + 2) * 128 + n];
      s3 += wv[kk][m + 3] * Wp[(m + 3) * 128 + n];
    }
    WcT[n * 384 + k] = f2bf(g1[k] * (s0 + s1 + s2 + s3));
  } else if (b == 192) {                // bc = bp + (bkv_v + b1@Wv)@Wp
    __shared__ float t[128];
    if (tid < 128) {
      float a0 = 0, a1 = 0, a2 = 0, a3 = 0;
#pragma unroll 8
      for (int k = 0; k < 384; k += 4) {
        a0 += b1[k]     * Wkv[(k)     * 256 + 128 + tid];
        a1 += b1[k + 1] * Wkv[(k + 1) * 256 + 128 + tid];
        a2 += b1[k + 2] * Wkv[(k + 2) * 256 + 128 + tid];
        a3 += b1[k + 3] * Wkv[(k + 3) * 256 + 128 + tid];
      }
      t[tid] = a0 + a1 + a2 + a3 + bkv[128 + tid];
    }
    __syncthreads();
    if (tid < 128) {
      float s = bp[tid];
#pragma unroll 8
      for (int m = 0; m < 128; ++m) s += t[m] * Wp[m * 128 + tid];
      bc[tid] = s;
    }
  } else if (b < 449) {                 // W1T halves, rows scaled by g2[k]
    const int id = (b - 193) * 256 + tid;
    const int n = id & 511, k = id >> 9;
    const short v = f2bf(W1[k * 512 + n] * g2[k]);
    if (n < 256) W1Ta[n * 128 + k] = v;
    else         W1Tb[(n - 256) * 128 + k] = v;
  } else if (b < 705) {                 // W2T, ch-chunked halves
    const int id = (b - 449) * 256 + tid;
    const int n = id & 127, k = id >> 7;
    const int ch = k >> 6, kk = k & 63;
    short* dst = (ch < 4) ? W2Ta : W2Tb;
    dst[((ch & 3) * 128 + n) * 64 + kk] = f2bf(W2[k * 128 + n]);
  } else {                              // bm1c = bm1 + b2@W1
    const int h = (b - 705) * 256 + tid;   // [0,512)
    float s = bm1[h];
#pragma unroll 8
    for (int k = 0; k < 128; ++k) s += b2[k] * W1[k * 512 + h];
    bm1c[h] = s;
  }
}

// ---------------- csscalc: colsum of the bf16 WcT (128 blocks x 64) ----------
__global__ void csscalc(const short* __restrict__ WcT, float* __restrict__ css) {
  const int n = blockIdx.x;             // [0,128)
  const int lane = threadIdx.x;         // [0,64)
  float s = 0.f;
  if (lane < 48) {
    bf16x8 v = *(const bf16x8*)(WcT + n * 384 + lane * 8);
#pragma unroll
    for (int j = 0; j < 8; ++j) s += bf2f(v[j]);
  }
  s += __shfl_xor(s, 1);  s += __shfl_xor(s, 2);  s += __shfl_xor(s, 4);
  s += __shfl_xor(s, 8);  s += __shfl_xor(s, 16); s += __shfl_xor(s, 32);
  if (lane == 0) css[n] = s;
}

// ---------------- fused: LN1@Wc + LN2 + MLP, M=32/wave, no barriers ----------
__global__ __launch_bounds__(256)
void fused(const float* __restrict__ x, const short* __restrict__ WcTg,
           const float* __restrict__ bcg, const float* __restrict__ cssg,
           const short* __restrict__ W1Tag, const short* __restrict__ W2Tag,
           const short* __restrict__ W1Tbg, const short* __restrict__ W2Tbg,
           const float* __restrict__ bm1c, const float* __restrict__ bm2g,
           float* __restrict__ out) {
  __shared__ __align__(16) short A3s[4][1152];  // per-wave, 576 per band
  const int tid = threadIdx.x, lane = tid & 63, w = tid >> 6;
  const int q = lane >> 4, c16 = lane & 15;
  const long band0 = (long)blockIdx.x * 8 + w * 2;  // wave owns bands band0, band0+1
  const float* xp0 = x + (band0 * 16 + c16) * 384 + q * 8;
  const float* xp1 = xp0 + 16 * 384;

  // ---- phase 1: y = LN1(x)@Wc + bc via linearity; each bfr feeds 2 MFMAs
  f32x4 yacc[2][8];
#pragma unroll
  for (int m = 0; m < 2; ++m)
#pragma unroll
    for (int t = 0; t < 8; ++t) yacc[m][t] = (f32x4){0.f, 0.f, 0.f, 0.f};
  float s0 = 0.f, sq0 = 0.f, s1 = 0.f, sq1 = 0.f;
#pragma unroll
  for (int ks = 0; ks < 12; ++ks) {
    const float4 va0 = *(const float4*)(xp0 + ks * 32);
    const float4 vb0 = *(const float4*)(xp0 + ks * 32 + 4);
    const float4 va1 = *(const float4*)(xp1 + ks * 32);
    const float4 vb1 = *(const float4*)(xp1 + ks * 32 + 4);
    s0  += va0.x + va0.y + va0.z + va0.w + vb0.x + vb0.y + vb0.z + vb0.w;
    sq0 += va0.x * va0.x + va0.y * va0.y + va0.z * va0.z + va0.w * va0.w
         + vb0.x * vb0.x + vb0.y * vb0.y + vb0.z * vb0.z + vb0.w * vb0.w;
    s1  += va1.x + va1.y + va1.z + va1.w + vb1.x + vb1.y + vb1.z + vb1.w;
    sq1 += va1.x * va1.x + va1.y * va1.y + va1.z * va1.z + va1.w * va1.w
         + vb1.x * vb1.x + vb1.y * vb1.y + vb1.z * vb1.z + vb1.w * vb1.w;
    bf16x8 f0, f1;
    f0[0] = f2bf(va0.x); f0[1] = f2bf(va0.y); f0[2] = f2bf(va0.z); f0[3] = f2bf(va0.w);
    f0[4] = f2bf(vb0.x); f0[5] = f2bf(vb0.y); f0[6] = f2bf(vb0.z); f0[7] = f2bf(vb0.w);
    f1[0] = f2bf(va1.x); f1[1] = f2bf(va1.y); f1[2] = f2bf(va1.z); f1[3] = f2bf(va1.w);
    f1[4] = f2bf(vb1.x); f1[5] = f2bf(vb1.y); f1[6] = f2bf(vb1.z); f1[7] = f2bf(vb1.w);
#pragma unroll
    for (int t = 0; t < 8; ++t) {
      bf16x8 bfr = *(const bf16x8*)(WcTg + (t * 16 + c16) * 384 + ks * 32 + q * 8);
      yacc[0][t] = __builtin_amdgcn_mfma_f32_16x16x32_bf16(f0, bfr, yacc[0][t], 0, 0, 0);
      yacc[1][t] = __builtin_amdgcn_mfma_f32_16x16x32_bf16(f1, bfr, yacc[1][t], 0, 0, 0);
    }
  }
  // LN1 stats per band
  s0  += __shfl_xor(s0, 16);  s0  += __shfl_xor(s0, 32);
  sq0 += __shfl_xor(sq0, 16); sq0 += __shfl_xor(sq0, 32);
  s1  += __shfl_xor(s1, 16);  s1  += __shfl_xor(s1, 32);
  sq1 += __shfl_xor(sq1, 16); sq1 += __shfl_xor(sq1, 32);
  const float mean0 = s0 * (1.f / 384.f);
  const float rs0 = rsqrtf(sq0 * (1.f / 384.f) - mean0 * mean0 + 1e-5f);
  const float mean1 = s1 * (1.f / 384.f);
  const float rs1 = rsqrtf(sq1 * (1.f / 384.f) - mean1 * mean1 + 1e-5f);
  float mr[2][4], rr[2][4];
#pragma unroll
  for (int r = 0; r < 4; ++r) {
    mr[0][r] = __shfl(mean0, q * 4 + r);
    rr[0][r] = __shfl(rs0,   q * 4 + r);
    mr[1][r] = __shfl(mean1, q * 4 + r);
    rr[1][r] = __shfl(rs1,   q * 4 + r);
  }

  // ---- finalize y = rr*(u - mr*colsum) + bc; LN2 stats
  float sm[2][4] = {{0,0,0,0},{0,0,0,0}}, sv[2][4] = {{0,0,0,0},{0,0,0,0}};
#pragma unroll
  for (int t = 0; t < 8; ++t) {
    const float cst = cssg[t * 16 + c16];
    const float bct = bcg[t * 16 + c16];
#pragma unroll
    for (int m = 0; m < 2; ++m)
#pragma unroll
      for (int r = 0; r < 4; ++r) {
        const float yv = rr[m][r] * (yacc[m][t][r] - mr[m][r] * cst) + bct;
        yacc[m][t][r] = yv; sm[m][r] += yv; sv[m][r] += yv * yv;
      }
  }
  float mn[2][4], rv[2][4];
#pragma unroll
  for (int m = 0; m < 2; ++m)
#pragma unroll
    for (int r = 0; r < 4; ++r) {
      sm[m][r] += __shfl_xor(sm[m][r], 1); sm[m][r] += __shfl_xor(sm[m][r], 2);
      sm[m][r] += __shfl_xor(sm[m][r], 4); sm[m][r] += __shfl_xor(sm[m][r], 8);
      sv[m][r] += __shfl_xor(sv[m][r], 1); sv[m][r] += __shfl_xor(sv[m][r], 2);
      sv[m][r] += __shfl_xor(sv[m][r], 4); sv[m][r] += __shfl_xor(sv[m][r], 8);
      mn[m][r] = sm[m][r] * (1.f / 128.f);
      rv[m][r] = rsqrtf(sv[m][r] * (1.f / 128.f) - mn[m][r] * mn[m][r] + 1e-5f);
    }

  // ---- bounce y-norm (g2/b2 folded) -> A-fragments, per band (own 576 half).
  // No explicit fences: write/read alias A3s (compiler keeps order), DS ops
  // execute in order within a wave, compiler inserts lgkmcnt before use.
  short* A3w = A3s[w];
  bf16x8 a2f[2][4];
#pragma unroll
  for (int m = 0; m < 2; ++m)
#pragma unroll
    for (int ks = 0; ks < 4; ++ks) {
#pragma unroll
      for (int tt = 0; tt < 2; ++tt) {
        const int t = ks * 2 + tt;
#pragma unroll
        for (int r = 0; r < 4; ++r)
          A3w[m * 576 + tt * 256 + r * 64 + q * 16 + c16] =
              f2bf((yacc[m][t][r] - mn[m][r]) * rv[m][r]);
      }
      a2f[m][ks] = *(const bf16x8*)(A3w + m * 576 + (q >> 1) * 256 +
                                    (c16 & 3) * 64 + (c16 >> 2) * 16 + (q & 1) * 8);
    }

  // ---- fold y (+bm2) into the MLP accumulator; yacc dies here
  f32x4 zacc[2][8];
#pragma unroll
  for (int t = 0; t < 8; ++t) {
    const float bb2 = bm2g[t * 16 + c16];
#pragma unroll
    for (int m = 0; m < 2; ++m)
#pragma unroll
      for (int r = 0; r < 4; ++r) zacc[m][t][r] = yacc[m][t][r] + bb2;
  }

  // ---- phase 2: MLP; every W1/W2 fragment feeds 2 MFMAs
#pragma unroll
  for (int half = 0; half < 2; ++half) {
    const short* W1g = half ? W1Tbg : W1Tag;
    const short* W2g = half ? W2Tbg : W2Tag;
#pragma unroll
    for (int ch = 0; ch < 4; ++ch) {
#pragma unroll
      for (int sub = 0; sub < 2; ++sub) {
        f32x4 hacc[2][2];
        hacc[0][0] = (f32x4){0.f,0.f,0.f,0.f}; hacc[0][1] = (f32x4){0.f,0.f,0.f,0.f};
        hacc[1][0] = (f32x4){0.f,0.f,0.f,0.f}; hacc[1][1] = (f32x4){0.f,0.f,0.f,0.f};
#pragma unroll
        for (int ks = 0; ks < 4; ++ks)
#pragma unroll
          for (int tt = 0; tt < 2; ++tt) {
            bf16x8 bfr = *(const bf16x8*)(W1g + (ch * 64 + sub * 32 + tt * 16 + c16) * 128 + ks * 32 + q * 8);
            hacc[0][tt] = __builtin_amdgcn_mfma_f32_16x16x32_bf16(a2f[0][ks], bfr, hacc[0][tt], 0, 0, 0);
            hacc[1][tt] = __builtin_amdgcn_mfma_f32_16x16x32_bf16(a2f[1][ks], bfr, hacc[1][tt], 0, 0, 0);
          }
        // preload W2 frags NOW (independent of the gelu/LDS exchange below)
        bf16x8 w2f[8];
#pragma unroll
        for (int t = 0; t < 8; ++t)
          w2f[t] = *(const bf16x8*)(W2g + (ch * 128 + t * 16 + c16) * 64 + sub * 32 + q * 8);
#pragma unroll
        for (int m = 0; m < 2; ++m)
#pragma unroll
          for (int tt = 0; tt < 2; ++tt) {
            const float bb = bm1c[half * 256 + ch * 64 + sub * 32 + tt * 16 + c16];
#pragma unroll
            for (int r = 0; r < 4; ++r) {
              const float h = hacc[m][tt][r] + bb;
              A3w[m * 576 + (q * 4 + r) * 36 + tt * 16 + c16] = f2bf(gelu_fast(h));
            }
          }
        bf16x8 af0 = *(const bf16x8*)(A3w + c16 * 36 + q * 8);
        bf16x8 af1 = *(const bf16x8*)(A3w + 576 + c16 * 36 + q * 8);
#pragma unroll
        for (int t = 0; t < 8; ++t) {
          zacc[0][t] = __builtin_amdgcn_mfma_f32_16x16x32_bf16(af0, w2f[t], zacc[0][t], 0, 0, 0);
          zacc[1][t] = __builtin_amdgcn_mfma_f32_16x16x32_bf16(af1, w2f[t], zacc[1][t], 0, 0, 0);
        }
      }
    }
  }

  // ---- epilogue: out = zacc (= y + mlp + bm2, all f32)
#pragma unroll
  for (int m = 0; m < 2; ++m)
#pragma unroll
    for (int r = 0; r < 4; ++r) {
      const long rowg = (band0 + m) * 16 + q * 4 + r;
#pragma unroll
      for (int t = 0; t < 8; ++t)
        out[rowg * 128 + t * 16 + c16] = zacc[m][t][r];
    }
}

extern "C" void kernel_launch(void* const* d_in, const int* in_sizes, int n_in,
                              void* d_out, int out_size, void* d_ws, size_t ws_size,
                              hipStream_t stream) {
  const float* x   = (const float*)d_in[0];
  const float* g1  = (const float*)d_in[1];
  const float* b1  = (const float*)d_in[2];
  // d_in[3]=Wq, [4]=bq, [7]=rpb dead (softmax over size-1 axis == 1)
  const float* Wkv = (const float*)d_in[5];
  const float* bkv = (const float*)d_in[6];
  const float* Wp  = (const float*)d_in[8];
  const float* bp  = (const float*)d_in[9];
  const float* g2  = (const float*)d_in[10];
  const float* b2  = (const float*)d_in[11];
  const float* W1  = (const float*)d_in[12];
  const float* bm1 = (const float*)d_in[13];
  const float* W2  = (const float*)d_in[14];
  const float* bm2 = (const float*)d_in[15];

  char* ws = (char*)d_ws;
  short* WcT  = (short*)(ws + 0);
  short* W1Ta = (short*)(ws + 98304);
  short* W2Ta = (short*)(ws + 163840);
  short* W1Tb = (short*)(ws + 229376);
  short* W2Tb = (short*)(ws + 294912);
  float* bc   = (float*)(ws + 360448);
  float* bm1c = (float*)(ws + 360960);
  float* css  = (float*)(ws + 363008);

  prep<<<707, 256, 0, stream>>>(Wkv, bkv, Wp, bp, W1, W2, g1, b1, g2, b2, bm1,
                                WcT, W1Ta, W1Tb, W2Ta, W2Tb, bc, bm1c);
  csscalc<<<128, 64, 0, stream>>>(WcT, css);
  fused<<<512, 256, 0, stream>>>(x, WcT, bc, css, W1Ta, W2Ta, W1Tb, W2Tb,
                                 bm1c, bm2, (float*)d_out);
}